// Round 1
// baseline (97.737 us; speedup 1.0000x reference)
//
#include <hip/hip_runtime.h>
#include <hip/hip_bf16.h>

// Quantum layer: 4 qubits, B=2^20 samples.
// state_out = V @ m  where V (16x16 complex) depends only on weights,
// m (16 real) = outer product of per-qubit (cos,sin) of x/2.
// out[w] = sum_j |state_out[j]|^2 * (1 - 2*bit_w(j)).

// ---------------- Kernel 1: build V from weights (16 threads) ----------------
__global__ void build_V_kernel(const float* __restrict__ w, float* __restrict__ V) {
    int k = threadIdx.x;
    if (k >= 16) return;

    // column k of the circuit unitary, in registers
    float ar[16], ai[16];
#pragma unroll
    for (int j = 0; j < 16; ++j) { ar[j] = (j == k) ? 1.f : 0.f; ai[j] = 0.f; }

#pragma unroll
    for (int l = 0; l < 3; ++l) {
        // --- Rot(phi, theta, omega) on each wire i ---
#pragma unroll
        for (int i = 0; i < 4; ++i) {
            float phi = w[l * 12 + i * 3 + 0];
            float th  = w[l * 12 + i * 3 + 1];
            float om  = w[l * 12 + i * 3 + 2];
            float ct = cosf(0.5f * th), st = sinf(0.5f * th);
            float alpha = 0.5f * (phi + om), beta = 0.5f * (phi - om);
            float sa, ca, sb, cb;
            sincosf(alpha, &sa, &ca);
            sincosf(beta,  &sb, &cb);
            // m00 = e^{-i a} ct, m01 = -e^{i b} st, m10 = e^{-i b} st, m11 = e^{i a} ct
            float m00r =  ca * ct, m00i = -sa * ct;
            float m01r = -cb * st, m01i = -sb * st;
            float m10r =  cb * st, m10i = -sb * st;
            float m11r =  ca * ct, m11i =  sa * ct;
            int mask = 1 << i;
#pragma unroll
            for (int j = 0; j < 16; ++j) {
                if (j & mask) continue;
                int j1 = j | mask;
                float a0r = ar[j],  a0i = ai[j];
                float a1r = ar[j1], a1i = ai[j1];
                ar[j]  = m00r * a0r - m00i * a0i + m01r * a1r - m01i * a1i;
                ai[j]  = m00r * a0i + m00i * a0r + m01r * a1i + m01i * a1r;
                ar[j1] = m10r * a0r - m10i * a0i + m11r * a1r - m11i * a1i;
                ai[j1] = m10r * a0i + m10i * a0r + m11r * a1i + m11i * a1r;
            }
        }
        // --- CNOT ring, range r = l%3 + 1; CNOT(c,t): swap j <-> j|tm where bit c set ---
        int r = (l % 3) + 1;
#pragma unroll
        for (int i = 0; i < 4; ++i) {
            int c = i, t = (i + r) & 3;
            int cm = 1 << c, tm = 1 << t;
#pragma unroll
            for (int j = 0; j < 16; ++j) {
                if ((j & cm) && !(j & tm)) {
                    int j2 = j | tm;
                    float tr = ar[j], ti = ai[j];
                    ar[j] = ar[j2]; ai[j] = ai[j2];
                    ar[j2] = tr;    ai[j2] = ti;
                }
            }
        }
    }

    // fold input phase (-i)^popcount(k) into column k
    int p = __popc(k) & 3;
    float pr = (p == 0) ? 1.f : (p == 2) ? -1.f : 0.f;
    float pi = (p == 1) ? -1.f : (p == 3) ? 1.f : 0.f;
#pragma unroll
    for (int j = 0; j < 16; ++j) {
        float vr = ar[j] * pr - ai[j] * pi;
        float vi = ar[j] * pi + ai[j] * pr;
        // layout: per output j: 16 re then 16 im, contiguous
        V[j * 32 + k]      = vr;
        V[j * 32 + 16 + k] = vi;
    }
}

// ---------------- Kernel 2: per-sample evaluation ----------------
#define SAMPLES_PER_THREAD 2
#define BLOCK 256

__launch_bounds__(BLOCK)
__global__ void qlayer_kernel(const float* __restrict__ x,
                              const float* __restrict__ Vg,
                              float* __restrict__ out, int B) {
    __shared__ float V[512];
    {
        int t = threadIdx.x;
        if (t < 128) ((float4*)V)[t] = ((const float4*)Vg)[t];
    }
    __syncthreads();

    int base = blockIdx.x * (BLOCK * SAMPLES_PER_THREAD) + threadIdx.x;

#pragma unroll
    for (int s = 0; s < SAMPLES_PER_THREAD; ++s) {
        int idx = base + s * BLOCK;
        if (idx < B) {
            float4 xv = ((const float4*)x)[idx];
            float c0, s0, c1, s1, c2, s2, c3, s3;
            __sincosf(0.5f * xv.x, &s0, &c0);
            __sincosf(0.5f * xv.y, &s1, &c1);
            __sincosf(0.5f * xv.z, &s2, &c2);
            __sincosf(0.5f * xv.w, &s3, &c3);

            // m[k]: bit w of k selects sin vs cos of wire w
            float m[16];
            m[0] = c0; m[1] = s0;
            m[2] = m[0] * s1; m[3] = m[1] * s1;
            m[0] *= c1;       m[1] *= c1;
#pragma unroll
            for (int k = 0; k < 4; ++k) { m[4 + k] = m[k] * s2; m[k] *= c2; }
#pragma unroll
            for (int k = 0; k < 8; ++k) { m[8 + k] = m[k] * s3; m[k] *= c3; }

            float z0 = 0.f, z1 = 0.f, z2 = 0.f, z3 = 0.f;
#pragma unroll
            for (int j = 0; j < 16; ++j) {
                float re = 0.f, im = 0.f;
#pragma unroll
                for (int k = 0; k < 16; ++k) {
                    re = fmaf(V[j * 32 + k],      m[k], re);
                    im = fmaf(V[j * 32 + 16 + k], m[k], im);
                }
                float p = fmaf(re, re, im * im);
                z0 += (j & 1) ? -p : p;
                z1 += (j & 2) ? -p : p;
                z2 += (j & 4) ? -p : p;
                z3 += (j & 8) ? -p : p;
            }
            float4 o; o.x = z0; o.y = z1; o.z = z2; o.w = z3;
            ((float4*)out)[idx] = o;
        }
    }
}

extern "C" void kernel_launch(void* const* d_in, const int* in_sizes, int n_in,
                              void* d_out, int out_size, void* d_ws, size_t ws_size,
                              hipStream_t stream) {
    const float* x = (const float*)d_in[0];
    const float* w = (const float*)d_in[1];
    float* out = (float*)d_out;
    float* V = (float*)d_ws;   // 512 floats

    int B = in_sizes[0] / 4;

    build_V_kernel<<<1, 64, 0, stream>>>(w, V);

    int samples_per_block = BLOCK * SAMPLES_PER_THREAD;
    int grid = (B + samples_per_block - 1) / samples_per_block;
    qlayer_kernel<<<grid, BLOCK, 0, stream>>>(x, V, out, B);
}